// Round 5
// baseline (885.803 us; speedup 1.0000x reference)
//
#include <hip/hip_runtime.h>
#include <math.h>

#define BB 64
#define TT 512
#define DD 2048
#define NBUF 16384
#define RND 10
#define DEC 0.9f
#define LN_DEC -0.10536051565782628f  /* ln(0.9) */
#define THRV 0.5f
#define RBLK 64  /* blocks in persistent round kernel (<= 256 CUs => co-resident) */

// ---------------- workspace layout (float offsets) ----------------
constexpr size_t OFF_L    = 0;                          // [RND][BB] row sum-exp per round (atomics, zeroed)
constexpr size_t OFF_ASUM = OFF_L + (size_t)RND * BB;   // [RND] active-sum per round (atomics, zeroed)
constexpr size_t OFF_BAR  = OFF_ASUM + RND;             // [4] barrier counter (zeroed)
constexpr size_t ZERO_FLOATS = OFF_BAR + 4;             // ~654 -> pad region start to 656
constexpr size_t OFF_ATOT = 656;                        // [BB][NBUF] sum_r coef_r*aw_r (fully written)
constexpr size_t OFF_BASE = OFF_ATOT + (size_t)BB * NBUF;  // [BB][NBUF] base_scores (fully written)
constexpr size_t OFF_ACC  = OFF_BASE + (size_t)BB * NBUF;  // [BB][DD] acc_pv
constexpr size_t OFF_POOL = OFF_ACC + (size_t)BB * DD;     // [BB][DD] pooled
constexpr size_t OFF_Q    = OFF_POOL + (size_t)BB * DD;    // [BB][DD] query pre-bias
constexpr size_t OFF_MSUM = OFF_Q + (size_t)BB * DD;       // [BB]
constexpr size_t OFF_VLD  = OFF_MSUM + 64;                 // [NBUF] normalized valid mask (0/1 float)
constexpr size_t OFF_PART = OFF_VLD + NBUF;                // [8][BB][DD] split partials (reused)
constexpr size_t WS_FLOATS = OFF_PART + (size_t)8 * BB * DD;

// ---------------- helpers ----------------
__device__ __forceinline__ float wave_sum(float v) {
#pragma unroll
  for (int o = 32; o; o >>= 1) v += __shfl_down(v, o);
  return v;
}

__device__ __forceinline__ float dev_wsum(const float* asum) {
  bool stopped = false; float w = 1.f, s = 0.f;
#pragma unroll
  for (int r = 0; r < RND; r++) {
    if (asum[r] < 0.5f) stopped = true;
    if (!stopped) s += w;
    w *= DEC;
  }
  return s;
}

// ---------------- valid-mask normalization (layout-robust) ----------------
// np.bool_ may land on device as 1-byte bools, int32, or float32. Detect:
// first 16 bytes all == 0x01  -> byte layout (read bytes, 16KB in-bounds).
// otherwise                   -> 4-byte elements (int32 1 or float32 1.0f are
//                                both nonzero dwords; 64KB in-bounds under
//                                that hypothesis). No OOB in either case.
__global__ __launch_bounds__(256) void k_valid(const void* __restrict__ valid, float* __restrict__ ws) {
  const unsigned char* vb = (const unsigned char*)valid;
  const unsigned int* vw = (const unsigned int*)valid;
  bool byte_layout = true;
#pragma unroll
  for (int i = 0; i < 16; i++) byte_layout = byte_layout && (vb[i] == (unsigned char)1);
  int n = blockIdx.x * 256 + threadIdx.x;
  float v = byte_layout ? (vb[n] ? 1.f : 0.f) : (vw[n] ? 1.f : 0.f);
  ws[OFF_VLD + n] = v;
}

// ---------------- mask row sums ----------------
__global__ __launch_bounds__(256) void k_msum(const float* __restrict__ mask, float* __restrict__ ws) {
  float* msum = ws + OFF_MSUM;
  int b = blockIdx.x, t = threadIdx.x;
  float s = mask[b * TT + t] + mask[b * TT + t + 256];
  s = wave_sum(s);
  __shared__ float red[4];
  if ((t & 63) == 0) red[t >> 6] = s;
  __syncthreads();
  if (t == 0) msum[b] = red[0] + red[1] + red[2] + red[3];
}

// ---------------- masked pooling (partials over 8 T-chunks of 64) ----------------
__global__ __launch_bounds__(256) void k_pool(const float* __restrict__ qs, const float* __restrict__ mask,
                                              float* __restrict__ ws) {
  float* part = ws + OFF_PART;
  int b = blockIdx.y;
  int d0 = blockIdx.x * 1024 + threadIdx.x * 4;
  int t0 = blockIdx.z * 64;
  __shared__ float ms[64];
  if (threadIdx.x < 64) ms[threadIdx.x] = mask[b * TT + t0 + threadIdx.x];
  __syncthreads();
  const float* p = qs + ((size_t)b * TT + t0) * DD + d0;
  float4 acc = make_float4(0.f, 0.f, 0.f, 0.f);
#pragma unroll 4
  for (int t = 0; t < 64; t++) {
    float m = ms[t];
    float4 v = *(const float4*)(p + (size_t)t * DD);
    acc.x = fmaf(v.x, m, acc.x); acc.y = fmaf(v.y, m, acc.y);
    acc.z = fmaf(v.z, m, acc.z); acc.w = fmaf(v.w, m, acc.w);
  }
  *(float4*)(part + ((size_t)blockIdx.z * BB + b) * DD + d0) = acc;
}

__global__ __launch_bounds__(256) void k_pooldiv(float* __restrict__ ws) {
  size_t i = (size_t)blockIdx.x * 256 + threadIdx.x;  // < BB*DD
  const float* part = ws + OFF_PART;
  const float* msum = ws + OFF_MSUM;
  float* pooled = ws + OFF_POOL;
  size_t BD = (size_t)BB * DD;
  float s = 0.f;
#pragma unroll
  for (int c = 0; c < 8; c++) s += part[c * BD + i];
  int b = (int)(i >> 11);
  pooled[i] = s / (msum[b] + 1e-8f);
}

// ---------------- GEMM building blocks (64x64 tile, BK=64, 256 thr, 4x4 frag) ----------------
__device__ __forceinline__ void stage_t(float* __restrict__ dst, const float* __restrict__ src, int ld) {
  int tr = threadIdx.x >> 2;
  int kb = (threadIdx.x & 3) << 4;
  const float* s = src + (size_t)tr * ld + kb;
#pragma unroll
  for (int q = 0; q < 4; q++) {
    float4 v = *(const float4*)(s + q * 4);
    int k = kb + q * 4;
    dst[(k + 0) * 68 + tr] = v.x;
    dst[(k + 1) * 68 + tr] = v.y;
    dst[(k + 2) * 68 + tr] = v.z;
    dst[(k + 3) * 68 + tr] = v.w;
  }
}

__device__ __forceinline__ void stage_t_bias(float* __restrict__ dst, const float* __restrict__ src, int ld,
                                             const float* __restrict__ bias) {
  int tr = threadIdx.x >> 2;
  int kb = (threadIdx.x & 3) << 4;
  const float* s = src + (size_t)tr * ld + kb;
#pragma unroll
  for (int q = 0; q < 4; q++) {
    float4 v = *(const float4*)(s + q * 4);
    float4 bv = *(const float4*)(bias + kb + q * 4);
    v.x += bv.x; v.y += bv.y; v.z += bv.z; v.w += bv.w;
    int k = kb + q * 4;
    dst[(k + 0) * 68 + tr] = v.x;
    dst[(k + 1) * 68 + tr] = v.y;
    dst[(k + 2) * 68 + tr] = v.z;
    dst[(k + 3) * 68 + tr] = v.w;
  }
}

__device__ __forceinline__ void stage_t_scale(float* __restrict__ dst, const float* __restrict__ src, int ld,
                                              float sc) {
  int tr = threadIdx.x >> 2;
  int kb = (threadIdx.x & 3) << 4;
  const float* s = src + (size_t)tr * ld + kb;
#pragma unroll
  for (int q = 0; q < 4; q++) {
    float4 v = *(const float4*)(s + q * 4);
    int k = kb + q * 4;
    dst[(k + 0) * 68 + tr] = v.x * sc;
    dst[(k + 1) * 68 + tr] = v.y * sc;
    dst[(k + 2) * 68 + tr] = v.z * sc;
    dst[(k + 3) * 68 + tr] = v.w * sc;
  }
}

__device__ __forceinline__ void stage_n(float* __restrict__ dst, const float* __restrict__ src, int ld) {
  int tr = threadIdx.x >> 2;
  int db = (threadIdx.x & 3) << 4;
  const float* s = src + (size_t)tr * ld + db;
  float* d = dst + tr * 68 + db;
#pragma unroll
  for (int q = 0; q < 4; q++) *(float4*)(d + q * 4) = *(const float4*)(s + q * 4);
}

__device__ __forceinline__ void gemm_core(const float* __restrict__ At, const float* __restrict__ Bt,
                                          float (&c)[4][4]) {
  const int tx = (threadIdx.x & 15) * 4;
  const int ty = (threadIdx.x >> 4) * 4;
#pragma unroll
  for (int k = 0; k < 64; k++) {
    float4 a = *(const float4*)(At + k * 68 + ty);
    float4 b = *(const float4*)(Bt + k * 68 + tx);
    c[0][0] = fmaf(a.x, b.x, c[0][0]); c[0][1] = fmaf(a.x, b.y, c[0][1]);
    c[0][2] = fmaf(a.x, b.z, c[0][2]); c[0][3] = fmaf(a.x, b.w, c[0][3]);
    c[1][0] = fmaf(a.y, b.x, c[1][0]); c[1][1] = fmaf(a.y, b.y, c[1][1]);
    c[1][2] = fmaf(a.y, b.z, c[1][2]); c[1][3] = fmaf(a.y, b.w, c[1][3]);
    c[2][0] = fmaf(a.z, b.x, c[2][0]); c[2][1] = fmaf(a.z, b.y, c[2][1]);
    c[2][2] = fmaf(a.z, b.z, c[2][2]); c[2][3] = fmaf(a.z, b.w, c[2][3]);
    c[3][0] = fmaf(a.w, b.x, c[3][0]); c[3][1] = fmaf(a.w, b.y, c[3][1]);
    c[3][2] = fmaf(a.w, b.z, c[3][2]); c[3][3] = fmaf(a.w, b.w, c[3][3]);
  }
}

// ---------------- query = pooled @ Wq^T (split-K partials) ----------------
__global__ __launch_bounds__(256) void k_wq(const float* __restrict__ Wq, float* __restrict__ ws) {
  __shared__ float At[64 * 68], Bt[64 * 68];
  const float* pooled = ws + OFF_POOL;
  float* part = ws + OFF_PART;
  int j0 = blockIdx.x * 64;
  int kc = blockIdx.y * 256;
  float c[4][4] = {};
  for (int kb = 0; kb < 256; kb += 64) {
    __syncthreads();
    stage_t(At, pooled + kc + kb, DD);
    stage_t(Bt, Wq + (size_t)j0 * DD + kc + kb, DD);
    __syncthreads();
    gemm_core(At, Bt, c);
  }
  int tx = (threadIdx.x & 15) * 4, ty = (threadIdx.x >> 4) * 4;
#pragma unroll
  for (int ii = 0; ii < 4; ii++) {
    float4 v = make_float4(c[ii][0], c[ii][1], c[ii][2], c[ii][3]);
    *(float4*)(part + ((size_t)blockIdx.y * BB + ty + ii) * DD + j0 + tx) = v;
  }
}

__global__ __launch_bounds__(256) void k_red8(float* __restrict__ dst, const float* __restrict__ ws) {
  size_t i = (size_t)blockIdx.x * 256 + threadIdx.x;
  const float* part = ws + OFF_PART;
  size_t BD = (size_t)BB * DD;
  float s = 0.f;
#pragma unroll
  for (int c = 0; c < 8; c++) s += part[c * BD + i];
  dst[i] = s;
}

// ---------------- base = (query+bq) @ keys^T * inv_sqrt_d ----------------
__global__ __launch_bounds__(256) void k_base(const float* __restrict__ keys, const float* __restrict__ bq,
                                              float* __restrict__ ws) {
  __shared__ float At[64 * 68], Bt[64 * 68];
  const float* qacc = ws + OFF_Q;
  float* base = ws + OFF_BASE;
  int n0 = blockIdx.x * 64;
  float c[4][4] = {};
  for (int kb = 0; kb < DD; kb += 64) {
    __syncthreads();
    stage_t_bias(At, qacc + kb, DD, bq + kb);
    stage_t(Bt, keys + (size_t)n0 * DD + kb, DD);
    __syncthreads();
    gemm_core(At, Bt, c);
  }
  const float sc = 0.022097086912079608f;  // 1/sqrt(2048)
  int tx = (threadIdx.x & 15) * 4, ty = (threadIdx.x >> 4) * 4;
#pragma unroll
  for (int ii = 0; ii < 4; ii++) {
    float4 v = make_float4(c[ii][0] * sc, c[ii][1] * sc, c[ii][2] * sc, c[ii][3] * sc);
    *(float4*)(base + (size_t)(ty + ii) * NBUF + n0 + tx) = v;
  }
}

// ---------------- persistent replay rounds (one kernel, software grid barrier) ----------------
// 64 blocks x 1024 threads; block bx owns n in [bx*256, bx*256+256).
// thread: nl = tid & 255 (n index), bq = tid >> 8 (b-quarter: 16 b's), sub = (tid>>6)&3.
__global__ __launch_bounds__(1024) void k_rounds(const float* __restrict__ prior,
                                                 const float* __restrict__ ages,
                                                 float* __restrict__ ws) {
  __shared__ float base_sh[64 * 256];  // 64KB: base[b][nl] slice
  __shared__ float wsh[256];           // block-local w_ages
  __shared__ float red[4][256];        // column-sum partials per bq
  __shared__ float red2[64][4];        // per-b wave partials (4 waves per bq)
  __shared__ float asq[4];
  __shared__ float rlsh[64];
  __shared__ float ash;
  float* lrow = ws + OFF_L;
  float* asum = ws + OFF_ASUM;
  unsigned int* bar = (unsigned int*)(ws + OFF_BAR);
  float* Atot = ws + OFF_ATOT;
  const float* base = ws + OFF_BASE;
  const float* vldbuf = ws + OFF_VLD;

  const int tid = threadIdx.x;
  const int nl = tid & 255, bq = tid >> 8;
  const int lane = tid & 63, sub = (tid >> 6) & 3;
  const int bx = blockIdx.x;
  const int n = bx * 256 + nl;

  // stage base tile [64][256] (coalesced float4)
#pragma unroll
  for (int i = 0; i < 4; i++) {
    int f = (i * 1024 + tid) * 4;
    int b = f >> 8, c = f & 255;
    *(float4*)(base_sh + b * 256 + c) = *(const float4*)(base + (size_t)b * NBUF + bx * 256 + c);
  }
  if (tid < 256) wsh[tid] = ages[bx * 256 + tid];
  const float pv = prior[n];
  const float vld = vldbuf[n];
  float atot[16];
#pragma unroll
  for (int i = 0; i < 16; i++) atot[i] = 0.f;
  float w = 1.f;
  bool stopped = false;
  __syncthreads();

  for (int r = 0; r < RND; r++) {
    // ---- phase A: e-sums per b (lrow[r]) and active-sum (asum[r]) ----
    const float wa = wsh[nl];
    const float eff = pv * __expf(wa * LN_DEC);
    const float act = vld / (1.f + __expf(-10.f * (eff - THRV)));
    const float g = act * eff;
#pragma unroll
    for (int bi = 0; bi < 16; bi++) {
      const int b = bq * 16 + bi;
      float e = vld * __expf(base_sh[b * 256 + nl] * g);
      e = wave_sum(e);
      if (lane == 0) red2[b][sub] = e;
    }
    if (bq == 0) {
      float s = wave_sum(act);
      if (lane == 0) asq[sub] = s;
    }
    __syncthreads();
    if (tid < 64) {
      __hip_atomic_fetch_add(lrow + (size_t)r * BB + tid,
                             red2[tid][0] + red2[tid][1] + red2[tid][2] + red2[tid][3],
                             __ATOMIC_RELEASE, __HIP_MEMORY_SCOPE_AGENT);
    } else if (tid == 64) {
      __hip_atomic_fetch_add(asum + r, asq[0] + asq[1] + asq[2] + asq[3],
                             __ATOMIC_RELEASE, __HIP_MEMORY_SCOPE_AGENT);
    }
    __syncthreads();
    // ---- grid barrier (monotone counter; ws zeroed each launch) ----
    if (tid == 0) {
      __hip_atomic_fetch_add(bar, 1u, __ATOMIC_RELEASE, __HIP_MEMORY_SCOPE_AGENT);
      const unsigned int target = (unsigned int)RBLK * (unsigned int)(r + 1);
      while (__hip_atomic_load(bar, __ATOMIC_ACQUIRE, __HIP_MEMORY_SCOPE_AGENT) < target)
        __builtin_amdgcn_s_sleep(2);
    }
    __syncthreads();
    if (tid < 64)
      rlsh[tid] = 1.f / __hip_atomic_load(lrow + (size_t)r * BB + tid,
                                          __ATOMIC_RELAXED, __HIP_MEMORY_SCOPE_AGENT);
    else if (tid == 64)
      ash = __hip_atomic_load(asum + r, __ATOMIC_RELAXED, __HIP_MEMORY_SCOPE_AGENT);
    __syncthreads();
    // ---- phase B: aw, Atot accumulation, age update ----
    stopped = stopped || (ash < 0.5f);
    const float coef = stopped ? 0.f : w;
    const float inc = stopped ? 0.f : 1.f;
    float csum = 0.f;
#pragma unroll
    for (int bi = 0; bi < 16; bi++) {
      const int b = bq * 16 + bi;
      const float e = vld * __expf(base_sh[b * 256 + nl] * g);
      const float aw = e * rlsh[b];
      atot[bi] = fmaf(coef, aw, atot[bi]);
      csum += aw;
    }
    red[bq][nl] = csum;
    __syncthreads();
    if (bq == 0)
      wsh[nl] = wa + inc * (red[0][nl] + red[1][nl] + red[2][nl] + red[3][nl]) * (1.f / 64.f);
    w *= DEC;
    __syncthreads();
  }
#pragma unroll
  for (int bi = 0; bi < 16; bi++) {
    const int b = bq * 16 + bi;
    Atot[(size_t)b * NBUF + n] = atot[bi];
  }
}

// ---------------- acc = A_total @ values (split over n-chunks) ----------------
__global__ __launch_bounds__(256) void k_pv(const float* __restrict__ values, float* __restrict__ ws) {
  __shared__ float At[64 * 68], Bt[64 * 68];
  const float* Atot = ws + OFF_ATOT;
  float* part = ws + OFF_PART;
  int d0 = blockIdx.x * 64;
  int nc = blockIdx.y * 2048;
  float c[4][4] = {};
  for (int kb = 0; kb < 2048; kb += 64) {
    __syncthreads();
    stage_t(At, Atot + nc + kb, NBUF);
    stage_n(Bt, values + (size_t)(nc + kb) * DD + d0, DD);
    __syncthreads();
    gemm_core(At, Bt, c);
  }
  int tx = (threadIdx.x & 15) * 4, ty = (threadIdx.x >> 4) * 4;
#pragma unroll
  for (int ii = 0; ii < 4; ii++) {
    float4 v = make_float4(c[ii][0], c[ii][1], c[ii][2], c[ii][3]);
    *(float4*)(part + ((size_t)blockIdx.y * BB + ty + ii) * DD + d0 + tx) = v;
  }
}

// ---------------- out = (acc/max(wsum,1e-8)) @ Wc^T (split-K partials) ----------------
__global__ __launch_bounds__(256) void k_wc(const float* __restrict__ Wc, float* __restrict__ ws) {
  __shared__ float At[64 * 68], Bt[64 * 68];
  const float* acc = ws + OFF_ACC;
  float rws = 1.f / fmaxf(dev_wsum(ws + OFF_ASUM), 1e-8f);
  float* part = ws + OFF_PART;
  int j0 = blockIdx.x * 64;
  int kc = blockIdx.y * 256;
  float c[4][4] = {};
  for (int kb = 0; kb < 256; kb += 64) {
    __syncthreads();
    stage_t_scale(At, acc + kc + kb, DD, rws);
    stage_t(Bt, Wc + (size_t)j0 * DD + kc + kb, DD);
    __syncthreads();
    gemm_core(At, Bt, c);
  }
  int tx = (threadIdx.x & 15) * 4, ty = (threadIdx.x >> 4) * 4;
#pragma unroll
  for (int ii = 0; ii < 4; ii++) {
    float4 v = make_float4(c[ii][0], c[ii][1], c[ii][2], c[ii][3]);
    *(float4*)(part + ((size_t)blockIdx.y * BB + ty + ii) * DD + j0 + tx) = v;
  }
}

__global__ __launch_bounds__(256) void k_red8_fin(float* __restrict__ out, const float* __restrict__ bc,
                                                  const float* __restrict__ ws) {
  size_t i = (size_t)blockIdx.x * 256 + threadIdx.x;
  const float* part = ws + OFF_PART;
  size_t BD = (size_t)BB * DD;
  float s = 0.f;
#pragma unroll
  for (int c = 0; c < 8; c++) s += part[c * BD + i];
  float wsv = dev_wsum(ws + OFF_ASUM);
  int j = (int)(i & (DD - 1));
  out[i] = (wsv > 0.f) ? (s + bc[j]) : 0.f;
}

// ---------------- launch ----------------
extern "C" void kernel_launch(void* const* d_in, const int* in_sizes, int n_in,
                              void* d_out, int out_size, void* d_ws, size_t ws_size,
                              hipStream_t stream) {
  (void)in_sizes; (void)n_in; (void)out_size; (void)ws_size;
  const float* qs    = (const float*)d_in[0];
  const float* mask  = (const float*)d_in[1];
  const float* keys  = (const float*)d_in[2];
  const float* vals  = (const float*)d_in[3];
  const float* prior = (const float*)d_in[4];
  const float* ages  = (const float*)d_in[5];
  const void*  valid = (const void*)d_in[6];
  const float* Wq = (const float*)d_in[7];
  const float* bq = (const float*)d_in[8];
  const float* Wc = (const float*)d_in[9];
  const float* bc = (const float*)d_in[10];
  float* out = (float*)d_out;
  float* ws  = (float*)d_ws;

  hipMemsetAsync(ws, 0, ZERO_FLOATS * sizeof(float), stream);  // lrow/asum/barrier only (~2.6KB)

  k_valid<<<NBUF / 256, 256, 0, stream>>>(valid, ws);
  k_msum<<<BB, 256, 0, stream>>>(mask, ws);
  k_pool<<<dim3(2, BB, 8), 256, 0, stream>>>(qs, mask, ws);
  k_pooldiv<<<(BB * DD) / 256, 256, 0, stream>>>(ws);
  k_wq<<<dim3(32, 8), 256, 0, stream>>>(Wq, ws);
  k_red8<<<(BB * DD) / 256, 256, 0, stream>>>(ws + OFF_Q, ws);
  k_base<<<NBUF / 64, 256, 0, stream>>>(keys, bq, ws);
  k_rounds<<<RBLK, 1024, 0, stream>>>(prior, ages, ws);
  k_pv<<<dim3(32, 8), 256, 0, stream>>>(vals, ws);
  k_red8<<<(BB * DD) / 256, 256, 0, stream>>>(ws + OFF_ACC, ws);
  k_wc<<<dim3(32, 8), 256, 0, stream>>>(Wc, ws);
  k_red8_fin<<<(BB * DD) / 256, 256, 0, stream>>>(out, bc, ws);
}

// Round 6
// 804.287 us; speedup vs baseline: 1.1014x; 1.1014x over previous
//
#include <hip/hip_runtime.h>
#include <math.h>

#define BB 64
#define TT 512
#define DD 2048
#define NBUF 16384
#define RND 10
#define DEC 0.9f
#define LN_DEC -0.10536051565782628f  /* ln(0.9) */
#define THRV 0.5f
#define RBLK 64  /* blocks in persistent round kernel (<= 256 CUs => co-resident) */

// ---------------- workspace layout (float offsets) ----------------
constexpr size_t OFF_L    = 0;                          // [RND][BB] row sum-exp per round (atomics, zeroed)
constexpr size_t OFF_ASUM = OFF_L + (size_t)RND * BB;   // [RND] active-sum per round (atomics, zeroed)
constexpr size_t OFF_BAR  = OFF_ASUM + RND;             // [4] barrier counter (zeroed)
constexpr size_t ZERO_FLOATS = OFF_BAR + 4;
constexpr size_t OFF_ATOT = 656;                        // [BB][NBUF] sum_r coef_r*aw_r
constexpr size_t OFF_BASE = OFF_ATOT + (size_t)BB * NBUF;  // [BB][NBUF] base_scores
constexpr size_t OFF_ACC  = OFF_BASE + (size_t)BB * NBUF;  // [BB][DD] acc_pv
constexpr size_t OFF_POOL = OFF_ACC + (size_t)BB * DD;     // [BB][DD] pooled
constexpr size_t OFF_Q    = OFF_POOL + (size_t)BB * DD;    // [BB][DD] query pre-bias
constexpr size_t OFF_MSUM = OFF_Q + (size_t)BB * DD;       // [BB]
constexpr size_t OFF_VLD  = OFF_MSUM + 64;                 // [NBUF] normalized valid mask
constexpr size_t OFF_PART = OFF_VLD + NBUF;                // [32][BB][DD] split partials (pool:8, wq:8, pv:32, wc:8)
constexpr size_t OFF_BPART= OFF_PART + (size_t)32 * BB * DD; // [4][BB][NBUF] k_base split-K partials
constexpr size_t WS_FLOATS = OFF_BPART + (size_t)4 * BB * NBUF;  // ~10.9M floats ≈ 44MB << 1GiB

// ---------------- helpers ----------------
__device__ __forceinline__ float wave_sum(float v) {
#pragma unroll
  for (int o = 32; o; o >>= 1) v += __shfl_down(v, o);
  return v;
}

__device__ __forceinline__ float dev_wsum(const float* asum) {
  bool stopped = false; float w = 1.f, s = 0.f;
#pragma unroll
  for (int r = 0; r < RND; r++) {
    if (asum[r] < 0.5f) stopped = true;
    if (!stopped) s += w;
    w *= DEC;
  }
  return s;
}

// ---------------- init: mask row sums (blocks 0..63) + valid normalize (blocks 64..127) ----------------
__global__ __launch_bounds__(256) void k_init(const float* __restrict__ mask, const void* __restrict__ valid,
                                              float* __restrict__ ws) {
  if (blockIdx.x < 64) {
    float* msum = ws + OFF_MSUM;
    int b = blockIdx.x, t = threadIdx.x;
    float s = mask[b * TT + t] + mask[b * TT + t + 256];
    s = wave_sum(s);
    __shared__ float red[4];
    if ((t & 63) == 0) red[t >> 6] = s;
    __syncthreads();
    if (t == 0) msum[b] = red[0] + red[1] + red[2] + red[3];
  } else {
    // valid_mask layout detect: first 16 bytes all 0x01 -> byte bools; else 4-byte elems.
    const unsigned char* vb = (const unsigned char*)valid;
    const unsigned int* vw = (const unsigned int*)valid;
    bool byte_layout = true;
#pragma unroll
    for (int i = 0; i < 16; i++) byte_layout = byte_layout && (vb[i] == (unsigned char)1);
    int n = (blockIdx.x - 64) * 256 + threadIdx.x;
    float v = byte_layout ? (vb[n] ? 1.f : 0.f) : (vw[n] ? 1.f : 0.f);
    ws[OFF_VLD + n] = v;
  }
}

// ---------------- masked pooling (partials over 8 T-chunks of 64) ----------------
__global__ __launch_bounds__(256) void k_pool(const float* __restrict__ qs, const float* __restrict__ mask,
                                              float* __restrict__ ws) {
  float* part = ws + OFF_PART;
  int b = blockIdx.y;
  int d0 = blockIdx.x * 1024 + threadIdx.x * 4;
  int t0 = blockIdx.z * 64;
  __shared__ float ms[64];
  if (threadIdx.x < 64) ms[threadIdx.x] = mask[b * TT + t0 + threadIdx.x];
  __syncthreads();
  const float* p = qs + ((size_t)b * TT + t0) * DD + d0;
  float4 acc = make_float4(0.f, 0.f, 0.f, 0.f);
#pragma unroll 4
  for (int t = 0; t < 64; t++) {
    float m = ms[t];
    float4 v = *(const float4*)(p + (size_t)t * DD);
    acc.x = fmaf(v.x, m, acc.x); acc.y = fmaf(v.y, m, acc.y);
    acc.z = fmaf(v.z, m, acc.z); acc.w = fmaf(v.w, m, acc.w);
  }
  *(float4*)(part + ((size_t)blockIdx.z * BB + b) * DD + d0) = acc;
}

__global__ __launch_bounds__(256) void k_pooldiv(float* __restrict__ ws) {
  size_t i4 = (size_t)blockIdx.x * 256 + threadIdx.x;  // < BB*DD/4
  const float4* part = (const float4*)(ws + OFF_PART);
  const float* msum = ws + OFF_MSUM;
  float4* pooled = (float4*)(ws + OFF_POOL);
  size_t BD4 = (size_t)BB * DD / 4;
  float4 s = make_float4(0.f, 0.f, 0.f, 0.f);
#pragma unroll
  for (int c = 0; c < 8; c++) {
    float4 v = part[c * BD4 + i4];
    s.x += v.x; s.y += v.y; s.z += v.z; s.w += v.w;
  }
  int b = (int)((i4 * 4) >> 11);
  float r = 1.f / (msum[b] + 1e-8f);
  s.x *= r; s.y *= r; s.z *= r; s.w *= r;
  pooled[i4] = s;
}

// ---------------- GEMM building blocks (64x64 tile, BK=64, 256 thr, 4x4 frag) ----------------
__device__ __forceinline__ void stage_t(float* __restrict__ dst, const float* __restrict__ src, int ld) {
  int tr = threadIdx.x >> 2;
  int kb = (threadIdx.x & 3) << 4;
  const float* s = src + (size_t)tr * ld + kb;
#pragma unroll
  for (int q = 0; q < 4; q++) {
    float4 v = *(const float4*)(s + q * 4);
    int k = kb + q * 4;
    dst[(k + 0) * 68 + tr] = v.x;
    dst[(k + 1) * 68 + tr] = v.y;
    dst[(k + 2) * 68 + tr] = v.z;
    dst[(k + 3) * 68 + tr] = v.w;
  }
}

__device__ __forceinline__ void stage_t_bias(float* __restrict__ dst, const float* __restrict__ src, int ld,
                                             const float* __restrict__ bias) {
  int tr = threadIdx.x >> 2;
  int kb = (threadIdx.x & 3) << 4;
  const float* s = src + (size_t)tr * ld + kb;
#pragma unroll
  for (int q = 0; q < 4; q++) {
    float4 v = *(const float4*)(s + q * 4);
    float4 bv = *(const float4*)(bias + kb + q * 4);
    v.x += bv.x; v.y += bv.y; v.z += bv.z; v.w += bv.w;
    int k = kb + q * 4;
    dst[(k + 0) * 68 + tr] = v.x;
    dst[(k + 1) * 68 + tr] = v.y;
    dst[(k + 2) * 68 + tr] = v.z;
    dst[(k + 3) * 68 + tr] = v.w;
  }
}

__device__ __forceinline__ void stage_t_scale(float* __restrict__ dst, const float* __restrict__ src, int ld,
                                              float sc) {
  int tr = threadIdx.x >> 2;
  int kb = (threadIdx.x & 3) << 4;
  const float* s = src + (size_t)tr * ld + kb;
#pragma unroll
  for (int q = 0; q < 4; q++) {
    float4 v = *(const float4*)(s + q * 4);
    int k = kb + q * 4;
    dst[(k + 0) * 68 + tr] = v.x * sc;
    dst[(k + 1) * 68 + tr] = v.y * sc;
    dst[(k + 2) * 68 + tr] = v.z * sc;
    dst[(k + 3) * 68 + tr] = v.w * sc;
  }
}

__device__ __forceinline__ void stage_n(float* __restrict__ dst, const float* __restrict__ src, int ld) {
  int tr = threadIdx.x >> 2;
  int db = (threadIdx.x & 3) << 4;
  const float* s = src + (size_t)tr * ld + db;
  float* d = dst + tr * 68 + db;
#pragma unroll
  for (int q = 0; q < 4; q++) *(float4*)(d + q * 4) = *(const float4*)(s + q * 4);
}

__device__ __forceinline__ void gemm_core(const float* __restrict__ At, const float* __restrict__ Bt,
                                          float (&c)[4][4]) {
  const int tx = (threadIdx.x & 15) * 4;
  const int ty = (threadIdx.x >> 4) * 4;
#pragma unroll
  for (int k = 0; k < 64; k++) {
    float4 a = *(const float4*)(At + k * 68 + ty);
    float4 b = *(const float4*)(Bt + k * 68 + tx);
    c[0][0] = fmaf(a.x, b.x, c[0][0]); c[0][1] = fmaf(a.x, b.y, c[0][1]);
    c[0][2] = fmaf(a.x, b.z, c[0][2]); c[0][3] = fmaf(a.x, b.w, c[0][3]);
    c[1][0] = fmaf(a.y, b.x, c[1][0]); c[1][1] = fmaf(a.y, b.y, c[1][1]);
    c[1][2] = fmaf(a.y, b.z, c[1][2]); c[1][3] = fmaf(a.y, b.w, c[1][3]);
    c[2][0] = fmaf(a.z, b.x, c[2][0]); c[2][1] = fmaf(a.z, b.y, c[2][1]);
    c[2][2] = fmaf(a.z, b.z, c[2][2]); c[2][3] = fmaf(a.z, b.w, c[2][3]);
    c[3][0] = fmaf(a.w, b.x, c[3][0]); c[3][1] = fmaf(a.w, b.y, c[3][1]);
    c[3][2] = fmaf(a.w, b.z, c[3][2]); c[3][3] = fmaf(a.w, b.w, c[3][3]);
  }
}

// ---------------- query = pooled @ Wq^T (split-K partials) ----------------
__global__ __launch_bounds__(256) void k_wq(const float* __restrict__ Wq, float* __restrict__ ws) {
  __shared__ float At[64 * 68], Bt[64 * 68];
  const float* pooled = ws + OFF_POOL;
  float* part = ws + OFF_PART;
  int j0 = blockIdx.x * 64;
  int kc = blockIdx.y * 256;
  float c[4][4] = {};
  for (int kb = 0; kb < 256; kb += 64) {
    __syncthreads();
    stage_t(At, pooled + kc + kb, DD);
    stage_t(Bt, Wq + (size_t)j0 * DD + kc + kb, DD);
    __syncthreads();
    gemm_core(At, Bt, c);
  }
  int tx = (threadIdx.x & 15) * 4, ty = (threadIdx.x >> 4) * 4;
#pragma unroll
  for (int ii = 0; ii < 4; ii++) {
    float4 v = make_float4(c[ii][0], c[ii][1], c[ii][2], c[ii][3]);
    *(float4*)(part + ((size_t)blockIdx.y * BB + ty + ii) * DD + j0 + tx) = v;
  }
}

// 8-chunk reduce: dst[BB*DD] = sum of 8 partials (for Q)
__global__ __launch_bounds__(256) void k_red8(float* __restrict__ dst, const float* __restrict__ ws) {
  size_t i4 = (size_t)blockIdx.x * 256 + threadIdx.x;  // < BB*DD/4
  const float4* part = (const float4*)(ws + OFF_PART);
  size_t BD4 = (size_t)BB * DD / 4;
  float4 s = make_float4(0.f, 0.f, 0.f, 0.f);
#pragma unroll
  for (int c = 0; c < 8; c++) {
    float4 v = part[c * BD4 + i4];
    s.x += v.x; s.y += v.y; s.z += v.z; s.w += v.w;
  }
  ((float4*)dst)[i4] = s;
}

// ---------------- base = (query+bq) @ keys^T * inv_sqrt_d (split-K x4) ----------------
__global__ __launch_bounds__(256) void k_base(const float* __restrict__ keys, const float* __restrict__ bq,
                                              float* __restrict__ ws) {
  __shared__ float At[64 * 68], Bt[64 * 68];
  const float* qacc = ws + OFF_Q;
  float* bpart = ws + OFF_BPART;
  int n0 = blockIdx.x * 64;
  int kc = blockIdx.y * 512;
  float c[4][4] = {};
  for (int kb = 0; kb < 512; kb += 64) {
    __syncthreads();
    stage_t_bias(At, qacc + kc + kb, DD, bq + kc + kb);
    stage_t(Bt, keys + (size_t)n0 * DD + kc + kb, DD);
    __syncthreads();
    gemm_core(At, Bt, c);
  }
  int tx = (threadIdx.x & 15) * 4, ty = (threadIdx.x >> 4) * 4;
#pragma unroll
  for (int ii = 0; ii < 4; ii++) {
    float4 v = make_float4(c[ii][0], c[ii][1], c[ii][2], c[ii][3]);
    *(float4*)(bpart + ((size_t)blockIdx.y * BB + ty + ii) * NBUF + n0 + tx) = v;
  }
}

// reduce 4 k-chunks -> base, applying 1/sqrt(D)
__global__ __launch_bounds__(256) void k_bred(float* __restrict__ ws) {
  size_t i4 = (size_t)blockIdx.x * 256 + threadIdx.x;  // < BB*NBUF/4
  const float4* bpart = (const float4*)(ws + OFF_BPART);
  float4* base = (float4*)(ws + OFF_BASE);
  size_t BN4 = (size_t)BB * NBUF / 4;
  const float sc = 0.022097086912079608f;  // 1/sqrt(2048)
  float4 s = make_float4(0.f, 0.f, 0.f, 0.f);
#pragma unroll
  for (int c = 0; c < 4; c++) {
    float4 v = bpart[c * BN4 + i4];
    s.x += v.x; s.y += v.y; s.z += v.z; s.w += v.w;
  }
  s.x *= sc; s.y *= sc; s.z *= sc; s.w *= sc;
  base[i4] = s;
}

// ---------------- persistent replay rounds (one kernel, software grid barrier) ----------------
__global__ __launch_bounds__(1024) void k_rounds(const float* __restrict__ prior,
                                                 const float* __restrict__ ages,
                                                 float* __restrict__ ws) {
  __shared__ float base_sh[64 * 256];  // 64KB: base[b][nl] slice
  __shared__ float wsh[256];
  __shared__ float red[4][256];
  __shared__ float red2[64][4];
  __shared__ float asq[4];
  __shared__ float rlsh[64];
  __shared__ float ash;
  float* lrow = ws + OFF_L;
  float* asum = ws + OFF_ASUM;
  unsigned int* bar = (unsigned int*)(ws + OFF_BAR);
  float* Atot = ws + OFF_ATOT;
  const float* base = ws + OFF_BASE;
  const float* vldbuf = ws + OFF_VLD;

  const int tid = threadIdx.x;
  const int nl = tid & 255, bq = tid >> 8;
  const int lane = tid & 63, sub = (tid >> 6) & 3;
  const int bx = blockIdx.x;
  const int n = bx * 256 + nl;

#pragma unroll
  for (int i = 0; i < 4; i++) {
    int f = (i * 1024 + tid) * 4;
    int b = f >> 8, c = f & 255;
    *(float4*)(base_sh + b * 256 + c) = *(const float4*)(base + (size_t)b * NBUF + bx * 256 + c);
  }
  if (tid < 256) wsh[tid] = ages[bx * 256 + tid];
  const float pv = prior[n];
  const float vld = vldbuf[n];
  float atot[16];
#pragma unroll
  for (int i = 0; i < 16; i++) atot[i] = 0.f;
  float w = 1.f;
  bool stopped = false;
  __syncthreads();

  for (int r = 0; r < RND; r++) {
    const float wa = wsh[nl];
    const float eff = pv * __expf(wa * LN_DEC);
    const float act = vld / (1.f + __expf(-10.f * (eff - THRV)));
    const float g = act * eff;
#pragma unroll
    for (int bi = 0; bi < 16; bi++) {
      const int b = bq * 16 + bi;
      float e = vld * __expf(base_sh[b * 256 + nl] * g);
      e = wave_sum(e);
      if (lane == 0) red2[b][sub] = e;
    }
    if (bq == 0) {
      float s = wave_sum(act);
      if (lane == 0) asq[sub] = s;
    }
    __syncthreads();
    if (tid < 64) {
      __hip_atomic_fetch_add(lrow + (size_t)r * BB + tid,
                             red2[tid][0] + red2[tid][1] + red2[tid][2] + red2[tid][3],
                             __ATOMIC_RELEASE, __HIP_MEMORY_SCOPE_AGENT);
    } else if (tid == 64) {
      __hip_atomic_fetch_add(asum + r, asq[0] + asq[1] + asq[2] + asq[3],
                             __ATOMIC_RELEASE, __HIP_MEMORY_SCOPE_AGENT);
    }
    __syncthreads();
    if (tid == 0) {
      __hip_atomic_fetch_add(bar, 1u, __ATOMIC_RELEASE, __HIP_MEMORY_SCOPE_AGENT);
      const unsigned int target = (unsigned int)RBLK * (unsigned int)(r + 1);
      while (__hip_atomic_load(bar, __ATOMIC_ACQUIRE, __HIP_MEMORY_SCOPE_AGENT) < target)
        __builtin_amdgcn_s_sleep(2);
    }
    __syncthreads();
    if (tid < 64)
      rlsh[tid] = 1.f / __hip_atomic_load(lrow + (size_t)r * BB + tid,
                                          __ATOMIC_RELAXED, __HIP_MEMORY_SCOPE_AGENT);
    else if (tid == 64)
      ash = __hip_atomic_load(asum + r, __ATOMIC_RELAXED, __HIP_MEMORY_SCOPE_AGENT);
    __syncthreads();
    stopped = stopped || (ash < 0.5f);
    const float coef = stopped ? 0.f : w;
    const float inc = stopped ? 0.f : 1.f;
    float csum = 0.f;
#pragma unroll
    for (int bi = 0; bi < 16; bi++) {
      const int b = bq * 16 + bi;
      const float e = vld * __expf(base_sh[b * 256 + nl] * g);
      const float aw = e * rlsh[b];
      atot[bi] = fmaf(coef, aw, atot[bi]);
      csum += aw;
    }
    red[bq][nl] = csum;
    __syncthreads();
    if (bq == 0)
      wsh[nl] = wa + inc * (red[0][nl] + red[1][nl] + red[2][nl] + red[3][nl]) * (1.f / 64.f);
    w *= DEC;
    __syncthreads();
  }
#pragma unroll
  for (int bi = 0; bi < 16; bi++) {
    const int b = bq * 16 + bi;
    Atot[(size_t)b * NBUF + n] = atot[bi];
  }
}

// ---------------- acc = A_total @ values (split over 32 n-chunks of 512) ----------------
__global__ __launch_bounds__(256) void k_pv(const float* __restrict__ values, float* __restrict__ ws) {
  __shared__ float At[64 * 68], Bt[64 * 68];
  const float* Atot = ws + OFF_ATOT;
  float* part = ws + OFF_PART;
  int d0 = blockIdx.x * 64;
  int nc = blockIdx.y * 512;
  float c[4][4] = {};
  for (int kb = 0; kb < 512; kb += 64) {
    __syncthreads();
    stage_t(At, Atot + nc + kb, NBUF);
    stage_n(Bt, values + (size_t)(nc + kb) * DD + d0, DD);
    __syncthreads();
    gemm_core(At, Bt, c);
  }
  int tx = (threadIdx.x & 15) * 4, ty = (threadIdx.x >> 4) * 4;
#pragma unroll
  for (int ii = 0; ii < 4; ii++) {
    float4 v = make_float4(c[ii][0], c[ii][1], c[ii][2], c[ii][3]);
    *(float4*)(part + ((size_t)blockIdx.y * BB + ty + ii) * DD + d0 + tx) = v;
  }
}

// reduce 32 n-chunks -> acc
__global__ __launch_bounds__(256) void k_red32(float* __restrict__ ws) {
  size_t i4 = (size_t)blockIdx.x * 256 + threadIdx.x;  // < BB*DD/4
  const float4* part = (const float4*)(ws + OFF_PART);
  float4* acc = (float4*)(ws + OFF_ACC);
  size_t BD4 = (size_t)BB * DD / 4;
  float4 s = make_float4(0.f, 0.f, 0.f, 0.f);
#pragma unroll
  for (int c = 0; c < 32; c++) {
    float4 v = part[c * BD4 + i4];
    s.x += v.x; s.y += v.y; s.z += v.z; s.w += v.w;
  }
  acc[i4] = s;
}

// ---------------- out = (acc/max(wsum,1e-8)) @ Wc^T (split-K partials) ----------------
__global__ __launch_bounds__(256) void k_wc(const float* __restrict__ Wc, float* __restrict__ ws) {
  __shared__ float At[64 * 68], Bt[64 * 68];
  const float* acc = ws + OFF_ACC;
  float rws = 1.f / fmaxf(dev_wsum(ws + OFF_ASUM), 1e-8f);
  float* part = ws + OFF_PART;
  int j0 = blockIdx.x * 64;
  int kc = blockIdx.y * 256;
  float c[4][4] = {};
  for (int kb = 0; kb < 256; kb += 64) {
    __syncthreads();
    stage_t_scale(At, acc + kc + kb, DD, rws);
    stage_t(Bt, Wc + (size_t)j0 * DD + kc + kb, DD);
    __syncthreads();
    gemm_core(At, Bt, c);
  }
  int tx = (threadIdx.x & 15) * 4, ty = (threadIdx.x >> 4) * 4;
#pragma unroll
  for (int ii = 0; ii < 4; ii++) {
    float4 v = make_float4(c[ii][0], c[ii][1], c[ii][2], c[ii][3]);
    *(float4*)(part + ((size_t)blockIdx.y * BB + ty + ii) * DD + j0 + tx) = v;
  }
}

__global__ __launch_bounds__(256) void k_red8_fin(float* __restrict__ out, const float* __restrict__ bc,
                                                  const float* __restrict__ ws) {
  size_t i4 = (size_t)blockIdx.x * 256 + threadIdx.x;  // < BB*DD/4
  const float4* part = (const float4*)(ws + OFF_PART);
  size_t BD4 = (size_t)BB * DD / 4;
  float4 s = make_float4(0.f, 0.f, 0.f, 0.f);
#pragma unroll
  for (int c = 0; c < 8; c++) {
    float4 v = part[c * BD4 + i4];
    s.x += v.x; s.y += v.y; s.z += v.z; s.w += v.w;
  }
  float wsv = dev_wsum(ws + OFF_ASUM);
  int j0 = (int)((i4 * 4) & (DD - 1));
  float4 bv = *(const float4*)(bc + j0);
  float4 o;
  if (wsv > 0.f) {
    o.x = s.x + bv.x; o.y = s.y + bv.y; o.z = s.z + bv.z; o.w = s.w + bv.w;
  } else {
    o = make_float4(0.f, 0.f, 0.f, 0.f);
  }
  ((float4*)out)[i4] = o;
}

// ---------------- launch ----------------
extern "C" void kernel_launch(void* const* d_in, const int* in_sizes, int n_in,
                              void* d_out, int out_size, void* d_ws, size_t ws_size,
                              hipStream_t stream) {
  (void)in_sizes; (void)n_in; (void)out_size; (void)ws_size;
  const float* qs    = (const float*)d_in[0];
  const float* mask  = (const float*)d_in[1];
  const float* keys  = (const float*)d_in[2];
  const float* vals  = (const float*)d_in[3];
  const float* prior = (const float*)d_in[4];
  const float* ages  = (const float*)d_in[5];
  const void*  valid = (const void*)d_in[6];
  const float* Wq = (const float*)d_in[7];
  const float* bq = (const float*)d_in[8];
  const float* Wc = (const float*)d_in[9];
  const float* bc = (const float*)d_in[10];
  float* out = (float*)d_out;
  float* ws  = (float*)d_ws;

  hipMemsetAsync(ws, 0, ZERO_FLOATS * sizeof(float), stream);  // lrow/asum/barrier only (~2.6KB)

  k_init<<<128, 256, 0, stream>>>(mask, valid, ws);
  k_pool<<<dim3(2, BB, 8), 256, 0, stream>>>(qs, mask, ws);
  k_pooldiv<<<(BB * DD / 4) / 256, 256, 0, stream>>>(ws);
  k_wq<<<dim3(32, 8), 256, 0, stream>>>(Wq, ws);
  k_red8<<<(BB * DD / 4) / 256, 256, 0, stream>>>(ws + OFF_Q, ws);
  k_base<<<dim3(NBUF / 64, 4), 256, 0, stream>>>(keys, bq, ws);     // 1024 blocks, 4/CU
  k_bred<<<(BB * NBUF / 4) / 256, 256, 0, stream>>>(ws);
  k_rounds<<<RBLK, 1024, 0, stream>>>(prior, ages, ws);
  k_pv<<<dim3(DD / 64, 32), 256, 0, stream>>>(vals, ws);            // 1024 blocks, 4/CU
  k_red32<<<(BB * DD / 4) / 256, 256, 0, stream>>>(ws);
  k_wc<<<dim3(32, 8), 256, 0, stream>>>(Wc, ws);
  k_red8_fin<<<(BB * DD / 4) / 256, 256, 0, stream>>>(out, bc, ws);
}